// Round 6
// baseline (836.258 us; speedup 1.0000x reference)
//
#include <hip/hip_runtime.h>
#include <hip/hip_bf16.h>

#define B 4
#define N_ALL 8192
#define N_VOX 4096
#define S_PTS 1024
#define K_SAMPLE 32
#define R2 0.04f

#define FPS_T 512                 // 8 waves: 4 per batch-half, 2 halves
#define HALF_T 256                // threads per batch half
#define NPAIR 8                   // 8 vf2 pairs = 16 points per thread
#define FPS_BLOCKS 2              // 2 batches per block
#define PREP_BLOCKS ((B * N_ALL) / FPS_T)   // 64

typedef float vf2 __attribute__((ext_vector_type(2)));

// Key = (dist_bits << 32) | ~idx, reinterpreted as double.
// dist in [0, 1e10] -> positive finite double, so v_max_f64 == u64 max.
// Keys unique (idx embedded); equal dists -> lowest idx (max ~idx) ==
// jnp.argmax tie-break.
__device__ __forceinline__ double mk_key(float v, unsigned int ilo) {
    return __longlong_as_double(
        ((unsigned long long)__float_as_uint(v) << 32) | ilo);
}

// Wave64 max via DPP + v_max_f64. Result valid in lane 63.
__device__ __forceinline__ double wave_key_max_f64(double k) {
    unsigned long long ku = __double_as_longlong(k);
#define DPP_RED(ctrl)                                                              \
    {                                                                              \
        unsigned int lo = (unsigned int)ku;                                        \
        unsigned int hi = (unsigned int)(ku >> 32);                                \
        unsigned int nlo =                                                         \
            (unsigned int)__builtin_amdgcn_update_dpp(0, (int)lo, ctrl, 0xf, 0xf, false); \
        unsigned int nhi =                                                         \
            (unsigned int)__builtin_amdgcn_update_dpp(0, (int)hi, ctrl, 0xf, 0xf, false); \
        double nk = __longlong_as_double(((unsigned long long)nhi << 32) | nlo);   \
        double cur = fmax(__longlong_as_double(ku), nk);                           \
        ku = __double_as_longlong(cur);                                            \
    }
    DPP_RED(0x111);  // row_shr:1
    DPP_RED(0x112);  // row_shr:2
    DPP_RED(0x114);  // row_shr:4
    DPP_RED(0x118);  // row_shr:8
    DPP_RED(0x142);  // row_bcast:15
    DPP_RED(0x143);  // row_bcast:31 -> lane 63 = all-64 max
#undef DPP_RED
    return __longlong_as_double(ku);
}

// ---------------------------------------------------------------------------
// Kernel 1: blocks 0..1 = FPS, TWO batches per block (waves 0-3 = batch
// 2*blk, waves 4-7 = batch 2*blk+1) so each SIMD hosts one wave of EACH
// batch — the serial reduce/barrier tail of one batch is hidden under the
// independent update issue of the other. Blocks 2.. pack (x,y,z,||p||^2)
// of xyz_all into d_ws. Per half-iter: exact distance update ((dx*dx +
// dy*dy) + dz*dz, contraction off), 15 v_max_f64 local tree, one DPP wave
// reduce, joint barrier (both halves at identical fixed trip count),
// ds_read_b128 partials + 3 v_max_f64, broadcast sp read.
// ---------------------------------------------------------------------------
__global__ __launch_bounds__(FPS_T, 1) void fps_prep_kernel(
    const float* __restrict__ xyz_voxel,
    const float* __restrict__ normals_voxel,
    const float* __restrict__ xyz_all,
    float* __restrict__ out_xyz,      // (B, S, 3)
    float* __restrict__ out_normals,  // (B, S, 3)
    float4* __restrict__ ws_packed,   // (B, N_ALL) {x,y,z,pp}
    int do_prep)
{
#pragma clang fp contract(off)
    if (blockIdx.x >= FPS_BLOCKS) {
        if (!do_prep) return;
        int pid = (blockIdx.x - FPS_BLOCKS) * FPS_T + threadIdx.x;
        if (pid < B * N_ALL) {
            float x = xyz_all[pid * 3 + 0];
            float y = xyz_all[pid * 3 + 1];
            float z = xyz_all[pid * 3 + 2];
            float pp = __fadd_rn(__fadd_rn(__fmul_rn(x, x), __fmul_rn(y, y)),
                                 __fmul_rn(z, z));
            ws_packed[pid] = make_float4(x, y, z, pp);
        }
        return;
    }

    const int t = threadIdx.x;
    const int half = t >> 8;            // 0 or 1: which batch of this block
    const int tl = t & (HALF_T - 1);    // 0..255 within the half
    const int b = blockIdx.x * 2 + half;
    const int wid = tl >> 6;            // 0..3 wave within half
    const int lane = t & 63;

    __shared__ float4 sp[2][N_VOX];                        // 2 x 64 KB
    __shared__ int fps_idx_s[2][S_PTS];                    // 8 KB
    __shared__ alignas(16) unsigned long long s_part[2][2][HALF_T / 64];

    const float* xyz = xyz_voxel + (size_t)b * N_VOX * 3;
    for (int i = tl; i < N_VOX; i += HALF_T) {
        float x = xyz[i * 3 + 0];
        float y = xyz[i * 3 + 1];
        float z = xyz[i * 3 + 2];
        sp[half][i] = make_float4(x, y, z, 0.0f);
    }
    __syncthreads();

    // Pair jp holds points (2jp)*256 + tl (lo) and (2jp+1)*256 + tl (hi).
    vf2 px2[NPAIR], py2[NPAIR], pz2[NPAIR], dist2[NPAIR];
    unsigned int ilo[2 * NPAIR];
#pragma unroll
    for (int jp = 0; jp < NPAIR; jp++) {
        float4 a = sp[half][tl + (2 * jp) * HALF_T];
        float4 c = sp[half][tl + (2 * jp + 1) * HALF_T];
        px2[jp] = vf2{a.x, c.x};
        py2[jp] = vf2{a.y, c.y};
        pz2[jp] = vf2{a.z, c.z};
        dist2[jp] = vf2{1e10f, 1e10f};
        ilo[2 * jp]     = ~(unsigned int)((2 * jp) * HALF_T + tl);
        ilo[2 * jp + 1] = ~(unsigned int)((2 * jp + 1) * HALF_T + tl);
    }

    if (tl == 0) fps_idx_s[half][0] = 0;
    float4 c0 = sp[half][0];
    float lx = c0.x, ly = c0.y, lz = c0.z;

    for (int step = 1; step < S_PTS; step++) {
        double kk[2 * NPAIR];
#pragma unroll
        for (int jp = 0; jp < NPAIR; jp++) {
            vf2 dx = px2[jp] - lx;
            vf2 dy = py2[jp] - ly;
            vf2 dz = pz2[jp] - lz;
            vf2 d = (dx * dx + dy * dy) + dz * dz;
            vf2 dm = dist2[jp];
            dm.x = fminf(dm.x, d.x);
            dm.y = fminf(dm.y, d.y);
            dist2[jp] = dm;
            kk[2 * jp]     = mk_key(dm.x, ilo[2 * jp]);
            kk[2 * jp + 1] = mk_key(dm.y, ilo[2 * jp + 1]);
        }
        // Local tree over 16 keys: 15 v_max_f64, depth 4.
        double m0 = fmax(fmax(kk[0], kk[1]),   fmax(kk[2], kk[3]));
        double m1 = fmax(fmax(kk[4], kk[5]),   fmax(kk[6], kk[7]));
        double m2 = fmax(fmax(kk[8], kk[9]),   fmax(kk[10], kk[11]));
        double m3 = fmax(fmax(kk[12], kk[13]), fmax(kk[14], kk[15]));
        double a0 = fmax(fmax(m0, m1), fmax(m2, m3));
        a0 = wave_key_max_f64(a0);

        const int buf = step & 1;
        if (lane == 63)
            s_part[half][buf][wid] = (unsigned long long)__double_as_longlong(a0);
        __syncthreads();
        // 4 partials: one ds_read_b128 pair + 3 v_max_f64, all threads.
        double2 q0 = *((const double2*)&s_part[half][buf][0]);
        double2 q1 = *((const double2*)&s_part[half][buf][2]);
        double p0 = fmax(fmax(q0.x, q0.y), fmax(q1.x, q1.y));
        int besti = (int)(~(unsigned int)(unsigned long long)__double_as_longlong(p0))
                    & (N_VOX - 1);
        float4 cb = sp[half][besti];         // broadcast b128 read
        lx = cb.x; ly = cb.y; lz = cb.z;
        if (tl == 0) fps_idx_s[half][step] = besti;
        // Double-buffered partials -> one barrier per iteration.
    }
    __syncthreads();

    for (int i = tl; i < S_PTS; i += HALF_T) {
        int idx = fps_idx_s[half][i];
        int o = (b * S_PTS + i) * 3;
        float4 c = sp[half][idx];
        out_xyz[o + 0] = c.x;
        out_xyz[o + 1] = c.y;
        out_xyz[o + 2] = c.z;
        const float* nv = normals_voxel + ((size_t)b * N_VOX + idx) * 3;
        out_normals[o + 0] = nv[0];
        out_normals[o + 1] = nv[1];
        out_normals[o + 2] = nv[2];
    }
}

// ---------------------------------------------------------------------------
// Kernel 2: ball query + grouping. One wave per query. Groups of 4 chunks:
// 4 independent float4 loads up front, 4 in-order ballots. Exact d2 form.
// ---------------------------------------------------------------------------
template <bool PACKED>
__global__ __launch_bounds__(256) void ballquery_group_kernel(
    const float* __restrict__ xyz_all,   // (B, N_ALL, 3)
    const float* __restrict__ normals,   // (B, N_ALL, 3)
    const float* __restrict__ new_xyz,   // (B, S, 3)
    const float4* __restrict__ pw,       // (B, N_ALL) packed
    float* __restrict__ out_feat,        // (B, 3, S, K)
    float* __restrict__ out_featn)       // (B, 6, S, K)
{
#pragma clang fp contract(off)
    const int wid = threadIdx.x >> 6;
    const int lane = threadIdx.x & 63;
    const int q = blockIdx.x * 4 + wid;
    const int b = q >> 10;
    const int s = q & 1023;

    const float* xyz = xyz_all + (size_t)b * N_ALL * 3;
    const float* nrm = normals + (size_t)b * N_ALL * 3;
    const float4* pwb = PACKED ? (pw + (size_t)b * N_ALL) : nullptr;

    const float qx = new_xyz[q * 3 + 0];
    const float qy = new_xyz[q * 3 + 1];
    const float qz = new_xyz[q * 3 + 2];
    const float qq = __fadd_rn(__fadd_rn(__fmul_rn(qx, qx), __fmul_rn(qy, qy)),
                               __fmul_rn(qz, qz));

    __shared__ int sidx[4][K_SAMPLE];

    int cnt = 0;
    if (PACKED) {
        for (int g = 0; g < N_ALL / 256 && cnt < K_SAMPLE; g++) {
            int base = g * 256 + lane;
            float4 c0 = pwb[base];
            float4 c1 = pwb[base + 64];
            float4 c2 = pwb[base + 128];
            float4 c3 = pwb[base + 192];
            vf2 pxA = vf2{c0.x, c1.x}, pxB = vf2{c2.x, c3.x};
            vf2 pyA = vf2{c0.y, c1.y}, pyB = vf2{c2.y, c3.y};
            vf2 pzA = vf2{c0.z, c1.z}, pzB = vf2{c2.z, c3.z};
            vf2 ppA = vf2{c0.w, c1.w}, ppB = vf2{c2.w, c3.w};
            vf2 dtA = qx * pxA; dtA = dtA + qy * pyA; dtA = dtA + qz * pzA;
            vf2 dtB = qx * pxB; dtB = dtB + qy * pyB; dtB = dtB + qz * pzB;
            vf2 d2A = (qq + ppA) - 2.0f * dtA;
            vf2 d2B = (qq + ppB) - 2.0f * dtB;
            float d2s[4] = {d2A.x, d2A.y, d2B.x, d2B.y};
#pragma unroll
            for (int u = 0; u < 4; u++) {
                bool hit = d2s[u] < R2;
                unsigned long long mask = __ballot(hit);
                if (hit) {
                    int pos = cnt + __popcll(mask & ((1ull << lane) - 1ull));
                    if (pos < K_SAMPLE) sidx[wid][pos] = g * 256 + u * 64 + lane;
                }
                cnt += (int)__popcll(mask);
            }
        }
    } else {
        for (int c = 0; c < N_ALL / 64 && cnt < K_SAMPLE; c++) {
            int i = c * 64 + lane;
            float px = xyz[i * 3 + 0];
            float py = xyz[i * 3 + 1];
            float pz = xyz[i * 3 + 2];
            float pp = __fadd_rn(__fadd_rn(__fmul_rn(px, px), __fmul_rn(py, py)),
                                 __fmul_rn(pz, pz));
            float dt = __fadd_rn(__fadd_rn(__fmul_rn(qx, px), __fmul_rn(qy, py)),
                                 __fmul_rn(qz, pz));
            float d2 = __fsub_rn(__fadd_rn(qq, pp), __fmul_rn(2.0f, dt));
            bool hit = d2 < R2;
            unsigned long long mask = __ballot(hit);
            if (hit) {
                int pos = cnt + __popcll(mask & ((1ull << lane) - 1ull));
                if (pos < K_SAMPLE) sidx[wid][pos] = i;
            }
            cnt += (int)__popcll(mask);
        }
    }
    __syncthreads();

    if (lane < K_SAMPLE) {
        int idxj;
        if (cnt == 0)        idxj = 0;
        else if (lane < cnt) idxj = sidx[wid][lane];
        else                 idxj = sidx[wid][0];

        float px, py, pz;
        if (PACKED) {
            float4 cc = pwb[idxj];
            px = cc.x; py = cc.y; pz = cc.z;
        } else {
            px = xyz[idxj * 3 + 0];
            py = xyz[idxj * 3 + 1];
            pz = xyz[idxj * 3 + 2];
        }
        float rx = __fsub_rn(px, qx);
        float ry = __fsub_rn(py, qy);
        float rz = __fsub_rn(pz, qz);

        int o3 = ((b * 3) * S_PTS + s) * K_SAMPLE + lane;
        out_feat[o3 + 0 * 32768] = rx;
        out_feat[o3 + 1 * 32768] = ry;
        out_feat[o3 + 2 * 32768] = rz;

        float nx = nrm[idxj * 3 + 0];
        float ny = nrm[idxj * 3 + 1];
        float nz = nrm[idxj * 3 + 2];

        int o4 = ((b * 6) * S_PTS + s) * K_SAMPLE + lane;
        out_featn[o4 + 0 * 32768] = rx;
        out_featn[o4 + 1 * 32768] = ry;
        out_featn[o4 + 2 * 32768] = rz;
        out_featn[o4 + 3 * 32768] = nx;
        out_featn[o4 + 4 * 32768] = ny;
        out_featn[o4 + 5 * 32768] = nz;
    }
}

extern "C" void kernel_launch(void* const* d_in, const int* in_sizes, int n_in,
                              void* d_out, int out_size, void* d_ws, size_t ws_size,
                              hipStream_t stream) {
    const float* xyz_all       = (const float*)d_in[0];
    const float* normals       = (const float*)d_in[1];
    const float* xyz_voxel     = (const float*)d_in[2];
    const float* normals_voxel = (const float*)d_in[3];

    float* out = (float*)d_out;
    float* out_xyz     = out;           // (4, 1024, 3)     = 12288
    float* out_normals = out + 12288;   // (4, 1024, 3)     = 12288
    float* out_feat    = out + 24576;   // (4, 3, 1024, 32) = 393216
    float* out_featn   = out + 417792;  // (4, 6, 1024, 32) = 786432

    const size_t need = (size_t)B * N_ALL * sizeof(float4);   // 512 KB
    const bool use_ws = ws_size >= need;

    fps_prep_kernel<<<FPS_BLOCKS + (use_ws ? PREP_BLOCKS : 0), FPS_T, 0, stream>>>(
        xyz_voxel, normals_voxel, xyz_all, out_xyz, out_normals,
        (float4*)d_ws, use_ws ? 1 : 0);

    if (use_ws) {
        ballquery_group_kernel<true><<<(B * S_PTS) / 4, 256, 0, stream>>>(
            xyz_all, normals, out_xyz, (const float4*)d_ws, out_feat, out_featn);
    } else {
        ballquery_group_kernel<false><<<(B * S_PTS) / 4, 256, 0, stream>>>(
            xyz_all, normals, out_xyz, nullptr, out_feat, out_featn);
    }
}

// Round 7
// 609.200 us; speedup vs baseline: 1.3727x; 1.3727x over previous
//
#include <hip/hip_runtime.h>
#include <hip/hip_bf16.h>

#define B 4
#define N_ALL 8192
#define N_VOX 4096
#define S_PTS 1024
#define K_SAMPLE 32
#define R2 0.04f

#define FPS_T 256                 // 4 waves = exactly 1 wave per SIMD
#define NPAIR 8                   // 8 vf2 pairs = 16 points per thread
#define PREP_BLOCKS ((B * N_ALL) / FPS_T)   // 128

typedef float vf2 __attribute__((ext_vector_type(2)));

// Forced packed fp32 ops (VOP3P). Per-half IEEE round-to-nearest — bit
// identical to scalar __fadd_rn/__fmul_rn. Plain syntax only (no modifiers).
__device__ __forceinline__ vf2 pk_add(vf2 a, vf2 b) {
    vf2 r;
    asm("v_pk_add_f32 %0, %1, %2" : "=v"(r) : "v"(a), "v"(b));
    return r;
}
__device__ __forceinline__ vf2 pk_mul(vf2 a, vf2 b) {
    vf2 r;
    asm("v_pk_mul_f32 %0, %1, %2" : "=v"(r) : "v"(a), "v"(b));
    return r;
}

// Key = (dist_bits << 32) | ~idx, reinterpreted as double.
// dist in [0, 1e10] -> positive finite double, so v_max_f64 == u64 max.
// Keys unique (idx embedded); equal dists -> lowest idx (max ~idx) ==
// jnp.argmax tie-break.
__device__ __forceinline__ double mk_key(float v, unsigned int ilo) {
    return __longlong_as_double(
        ((unsigned long long)__float_as_uint(v) << 32) | ilo);
}

// Wave64 max via DPP + v_max_f64. Result valid in lane 63.
__device__ __forceinline__ double wave_key_max_f64(double k) {
    unsigned long long ku = __double_as_longlong(k);
#define DPP_RED(ctrl)                                                              \
    {                                                                              \
        unsigned int lo = (unsigned int)ku;                                        \
        unsigned int hi = (unsigned int)(ku >> 32);                                \
        unsigned int nlo =                                                         \
            (unsigned int)__builtin_amdgcn_update_dpp(0, (int)lo, ctrl, 0xf, 0xf, false); \
        unsigned int nhi =                                                         \
            (unsigned int)__builtin_amdgcn_update_dpp(0, (int)hi, ctrl, 0xf, 0xf, false); \
        double nk = __longlong_as_double(((unsigned long long)nhi << 32) | nlo);   \
        double cur = fmax(__longlong_as_double(ku), nk);                           \
        ku = __double_as_longlong(cur);                                            \
    }
    DPP_RED(0x111);  // row_shr:1
    DPP_RED(0x112);  // row_shr:2
    DPP_RED(0x114);  // row_shr:4
    DPP_RED(0x118);  // row_shr:8
    DPP_RED(0x142);  // row_bcast:15
    DPP_RED(0x143);  // row_bcast:31 -> lane 63 = all-64 max
#undef DPP_RED
    return __longlong_as_double(ku);
}

// ---------------------------------------------------------------------------
// Kernel 1: blocks 0..3 = FPS (one block per batch, 256 threads = 1 wave per
// SIMD — R6 proved 2 waves/SIMD serialize on the issue port); blocks 4..
// pack (x,y,z,||p||^2) of xyz_all into d_ws.
// Per iter: forced-pk distance update (sub as exact sign-flip add;
// (dx*dx + dy*dy) + dz*dz association preserved), scalar v_min_f32 running
// min, 16 f64-key build + 15 v_max_f64 tree, one DPP wave reduce, 4-wave
// barrier, ds_read_b128 partials + 3 v_max_f64, broadcast sp read.
// ---------------------------------------------------------------------------
__global__ __launch_bounds__(FPS_T, 1) void fps_prep_kernel(
    const float* __restrict__ xyz_voxel,
    const float* __restrict__ normals_voxel,
    const float* __restrict__ xyz_all,
    float* __restrict__ out_xyz,      // (B, S, 3)
    float* __restrict__ out_normals,  // (B, S, 3)
    float4* __restrict__ ws_packed,   // (B, N_ALL) {x,y,z,pp}
    int do_prep)
{
#pragma clang fp contract(off)
    if (blockIdx.x >= B) {
        if (!do_prep) return;
        int pid = (blockIdx.x - B) * FPS_T + threadIdx.x;
        if (pid < B * N_ALL) {
            float x = xyz_all[pid * 3 + 0];
            float y = xyz_all[pid * 3 + 1];
            float z = xyz_all[pid * 3 + 2];
            float pp = __fadd_rn(__fadd_rn(__fmul_rn(x, x), __fmul_rn(y, y)),
                                 __fmul_rn(z, z));
            ws_packed[pid] = make_float4(x, y, z, pp);
        }
        return;
    }

    const int b = blockIdx.x;
    const int t = threadIdx.x;
    const int wid = t >> 6;    // 0..3
    const int lane = t & 63;

    __shared__ float4 sp[N_VOX];                       // 64 KB
    __shared__ int fps_idx_s[S_PTS];
    __shared__ alignas(16) unsigned long long s_part[2][FPS_T / 64];

    const float* xyz = xyz_voxel + (size_t)b * N_VOX * 3;
    for (int i = t; i < N_VOX; i += FPS_T) {
        float x = xyz[i * 3 + 0];
        float y = xyz[i * 3 + 1];
        float z = xyz[i * 3 + 2];
        sp[i] = make_float4(x, y, z, 0.0f);
    }
    __syncthreads();

    // Pair jp holds global points (2jp)*256 + t (lo half) and
    // (2jp+1)*256 + t (hi half).
    vf2 px2[NPAIR], py2[NPAIR], pz2[NPAIR];
    float dist[2 * NPAIR];
    unsigned int ilo[2 * NPAIR];
#pragma unroll
    for (int jp = 0; jp < NPAIR; jp++) {
        float4 a = sp[t + (2 * jp) * FPS_T];
        float4 c = sp[t + (2 * jp + 1) * FPS_T];
        px2[jp] = vf2{a.x, c.x};
        py2[jp] = vf2{a.y, c.y};
        pz2[jp] = vf2{a.z, c.z};
        dist[2 * jp] = 1e10f;
        dist[2 * jp + 1] = 1e10f;
        ilo[2 * jp]     = ~(unsigned int)((2 * jp) * FPS_T + t);
        ilo[2 * jp + 1] = ~(unsigned int)((2 * jp + 1) * FPS_T + t);
    }

    if (t == 0) fps_idx_s[0] = 0;
    float4 c0 = sp[0];
    float lx = c0.x, ly = c0.y, lz = c0.z;

    for (int step = 1; step < S_PTS; step++) {
        // Exact negation (sign flip) -> px + (-lx) == px - lx bit-exactly.
        float nlx = __uint_as_float(__float_as_uint(lx) ^ 0x80000000u);
        float nly = __uint_as_float(__float_as_uint(ly) ^ 0x80000000u);
        float nlz = __uint_as_float(__float_as_uint(lz) ^ 0x80000000u);
        vf2 nlxx = vf2{nlx, nlx};
        vf2 nlyy = vf2{nly, nly};
        vf2 nlzz = vf2{nlz, nlz};
#pragma unroll
        for (int jp = 0; jp < NPAIR; jp++) {
            vf2 dx = pk_add(px2[jp], nlxx);
            vf2 dy = pk_add(py2[jp], nlyy);
            vf2 dz = pk_add(pz2[jp], nlzz);
            vf2 d = pk_add(pk_add(pk_mul(dx, dx), pk_mul(dy, dy)),
                           pk_mul(dz, dz));
            dist[2 * jp]     = fminf(dist[2 * jp], d.x);
            dist[2 * jp + 1] = fminf(dist[2 * jp + 1], d.y);
        }
        // Build 16 keys, reduce with 15 v_max_f64 (depth 4).
        double kk[2 * NPAIR];
#pragma unroll
        for (int i = 0; i < 2 * NPAIR; i++) kk[i] = mk_key(dist[i], ilo[i]);
        double m0 = fmax(fmax(kk[0], kk[1]),   fmax(kk[2], kk[3]));
        double m1 = fmax(fmax(kk[4], kk[5]),   fmax(kk[6], kk[7]));
        double m2 = fmax(fmax(kk[8], kk[9]),   fmax(kk[10], kk[11]));
        double m3 = fmax(fmax(kk[12], kk[13]), fmax(kk[14], kk[15]));
        double a0 = fmax(fmax(m0, m1), fmax(m2, m3));
        a0 = wave_key_max_f64(a0);

        const int buf = step & 1;
        if (lane == 63)
            s_part[buf][wid] = (unsigned long long)__double_as_longlong(a0);
        __syncthreads();
        // 4 partials: ds_read_b128 pair + 3 v_max_f64, all threads.
        double2 q0 = *((const double2*)&s_part[buf][0]);
        double2 q1 = *((const double2*)&s_part[buf][2]);
        double p0 = fmax(fmax(q0.x, q0.y), fmax(q1.x, q1.y));
        int besti = (int)(~(unsigned int)(unsigned long long)__double_as_longlong(p0))
                    & (N_VOX - 1);
        float4 cb = sp[besti];               // broadcast b128 read
        lx = cb.x; ly = cb.y; lz = cb.z;
        if (t == 0) fps_idx_s[step] = besti;
        // Double-buffered partials -> one barrier per iteration.
    }
    __syncthreads();

    for (int i = t; i < S_PTS; i += FPS_T) {
        int idx = fps_idx_s[i];
        int o = (b * S_PTS + i) * 3;
        float4 c = sp[idx];
        out_xyz[o + 0] = c.x;
        out_xyz[o + 1] = c.y;
        out_xyz[o + 2] = c.z;
        const float* nv = normals_voxel + ((size_t)b * N_VOX + idx) * 3;
        out_normals[o + 0] = nv[0];
        out_normals[o + 1] = nv[1];
        out_normals[o + 2] = nv[2];
    }
}

// ---------------------------------------------------------------------------
// Kernel 2: ball query + grouping. One wave per query. Groups of 4 chunks:
// 4 independent float4 loads up front, 4 in-order ballots. Exact d2 form.
// ---------------------------------------------------------------------------
template <bool PACKED>
__global__ __launch_bounds__(256) void ballquery_group_kernel(
    const float* __restrict__ xyz_all,   // (B, N_ALL, 3)
    const float* __restrict__ normals,   // (B, N_ALL, 3)
    const float* __restrict__ new_xyz,   // (B, S, 3)
    const float4* __restrict__ pw,       // (B, N_ALL) packed
    float* __restrict__ out_feat,        // (B, 3, S, K)
    float* __restrict__ out_featn)       // (B, 6, S, K)
{
#pragma clang fp contract(off)
    const int wid = threadIdx.x >> 6;
    const int lane = threadIdx.x & 63;
    const int q = blockIdx.x * 4 + wid;
    const int b = q >> 10;
    const int s = q & 1023;

    const float* xyz = xyz_all + (size_t)b * N_ALL * 3;
    const float* nrm = normals + (size_t)b * N_ALL * 3;
    const float4* pwb = PACKED ? (pw + (size_t)b * N_ALL) : nullptr;

    const float qx = new_xyz[q * 3 + 0];
    const float qy = new_xyz[q * 3 + 1];
    const float qz = new_xyz[q * 3 + 2];
    const float qq = __fadd_rn(__fadd_rn(__fmul_rn(qx, qx), __fmul_rn(qy, qy)),
                               __fmul_rn(qz, qz));

    __shared__ int sidx[4][K_SAMPLE];

    int cnt = 0;
    if (PACKED) {
        for (int g = 0; g < N_ALL / 256 && cnt < K_SAMPLE; g++) {
            int base = g * 256 + lane;
            float4 c0 = pwb[base];
            float4 c1 = pwb[base + 64];
            float4 c2 = pwb[base + 128];
            float4 c3 = pwb[base + 192];
            vf2 pxA = vf2{c0.x, c1.x}, pxB = vf2{c2.x, c3.x};
            vf2 pyA = vf2{c0.y, c1.y}, pyB = vf2{c2.y, c3.y};
            vf2 pzA = vf2{c0.z, c1.z}, pzB = vf2{c2.z, c3.z};
            vf2 ppA = vf2{c0.w, c1.w}, ppB = vf2{c2.w, c3.w};
            vf2 dtA = qx * pxA; dtA = dtA + qy * pyA; dtA = dtA + qz * pzA;
            vf2 dtB = qx * pxB; dtB = dtB + qy * pyB; dtB = dtB + qz * pzB;
            vf2 d2A = (qq + ppA) - 2.0f * dtA;
            vf2 d2B = (qq + ppB) - 2.0f * dtB;
            float d2s[4] = {d2A.x, d2A.y, d2B.x, d2B.y};
#pragma unroll
            for (int u = 0; u < 4; u++) {
                bool hit = d2s[u] < R2;
                unsigned long long mask = __ballot(hit);
                if (hit) {
                    int pos = cnt + __popcll(mask & ((1ull << lane) - 1ull));
                    if (pos < K_SAMPLE) sidx[wid][pos] = g * 256 + u * 64 + lane;
                }
                cnt += (int)__popcll(mask);
            }
        }
    } else {
        for (int c = 0; c < N_ALL / 64 && cnt < K_SAMPLE; c++) {
            int i = c * 64 + lane;
            float px = xyz[i * 3 + 0];
            float py = xyz[i * 3 + 1];
            float pz = xyz[i * 3 + 2];
            float pp = __fadd_rn(__fadd_rn(__fmul_rn(px, px), __fmul_rn(py, py)),
                                 __fmul_rn(pz, pz));
            float dt = __fadd_rn(__fadd_rn(__fmul_rn(qx, px), __fmul_rn(qy, py)),
                                 __fmul_rn(qz, pz));
            float d2 = __fsub_rn(__fadd_rn(qq, pp), __fmul_rn(2.0f, dt));
            bool hit = d2 < R2;
            unsigned long long mask = __ballot(hit);
            if (hit) {
                int pos = cnt + __popcll(mask & ((1ull << lane) - 1ull));
                if (pos < K_SAMPLE) sidx[wid][pos] = i;
            }
            cnt += (int)__popcll(mask);
        }
    }
    __syncthreads();

    if (lane < K_SAMPLE) {
        int idxj;
        if (cnt == 0)        idxj = 0;
        else if (lane < cnt) idxj = sidx[wid][lane];
        else                 idxj = sidx[wid][0];

        float px, py, pz;
        if (PACKED) {
            float4 cc = pwb[idxj];
            px = cc.x; py = cc.y; pz = cc.z;
        } else {
            px = xyz[idxj * 3 + 0];
            py = xyz[idxj * 3 + 1];
            pz = xyz[idxj * 3 + 2];
        }
        float rx = __fsub_rn(px, qx);
        float ry = __fsub_rn(py, qy);
        float rz = __fsub_rn(pz, qz);

        int o3 = ((b * 3) * S_PTS + s) * K_SAMPLE + lane;
        out_feat[o3 + 0 * 32768] = rx;
        out_feat[o3 + 1 * 32768] = ry;
        out_feat[o3 + 2 * 32768] = rz;

        float nx = nrm[idxj * 3 + 0];
        float ny = nrm[idxj * 3 + 1];
        float nz = nrm[idxj * 3 + 2];

        int o4 = ((b * 6) * S_PTS + s) * K_SAMPLE + lane;
        out_featn[o4 + 0 * 32768] = rx;
        out_featn[o4 + 1 * 32768] = ry;
        out_featn[o4 + 2 * 32768] = rz;
        out_featn[o4 + 3 * 32768] = nx;
        out_featn[o4 + 4 * 32768] = ny;
        out_featn[o4 + 5 * 32768] = nz;
    }
}

extern "C" void kernel_launch(void* const* d_in, const int* in_sizes, int n_in,
                              void* d_out, int out_size, void* d_ws, size_t ws_size,
                              hipStream_t stream) {
    const float* xyz_all       = (const float*)d_in[0];
    const float* normals       = (const float*)d_in[1];
    const float* xyz_voxel     = (const float*)d_in[2];
    const float* normals_voxel = (const float*)d_in[3];

    float* out = (float*)d_out;
    float* out_xyz     = out;           // (4, 1024, 3)     = 12288
    float* out_normals = out + 12288;   // (4, 1024, 3)     = 12288
    float* out_feat    = out + 24576;   // (4, 3, 1024, 32) = 393216
    float* out_featn   = out + 417792;  // (4, 6, 1024, 32) = 786432

    const size_t need = (size_t)B * N_ALL * sizeof(float4);   // 512 KB
    const bool use_ws = ws_size >= need;

    fps_prep_kernel<<<B + (use_ws ? PREP_BLOCKS : 0), FPS_T, 0, stream>>>(
        xyz_voxel, normals_voxel, xyz_all, out_xyz, out_normals,
        (float4*)d_ws, use_ws ? 1 : 0);

    if (use_ws) {
        ballquery_group_kernel<true><<<(B * S_PTS) / 4, 256, 0, stream>>>(
            xyz_all, normals, out_xyz, (const float4*)d_ws, out_feat, out_featn);
    } else {
        ballquery_group_kernel<false><<<(B * S_PTS) / 4, 256, 0, stream>>>(
            xyz_all, normals, out_xyz, nullptr, out_feat, out_featn);
    }
}

// Round 9
// 584.232 us; speedup vs baseline: 1.4314x; 1.0427x over previous
//
#include <hip/hip_runtime.h>
#include <hip/hip_bf16.h>

#define B 4
#define N_ALL 8192
#define N_VOX 4096
#define S_PTS 1024
#define K_SAMPLE 32
#define R2 0.04f

#define FPS_T 256                 // 4 waves = exactly 1 wave per SIMD
#define NPAIR 8                   // 8 vf2 pairs = 16 points per thread
#define PREP_BLOCKS ((B * N_ALL) / FPS_T)   // 128

typedef float vf2 __attribute__((ext_vector_type(2)));

// Key = (dist_bits << 32) | ~idx, reinterpreted as double.
// dist in [0, 1e10] -> positive finite double, so v_max_f64 == u64 max.
// Keys unique (idx embedded); equal dists -> lowest idx (max ~idx) ==
// jnp.argmax tie-break.
__device__ __forceinline__ double mk_key(float v, unsigned int ilo) {
    return __longlong_as_double(
        ((unsigned long long)__float_as_uint(v) << 32) | ilo);
}

// Wave64 max via DPP + v_max_f64. Result valid in lane 63.
// old=0 for sourceless lanes -> +0.0 key, loses to every real key.
__device__ __forceinline__ double wave_key_max_f64(double k) {
    unsigned long long ku = __double_as_longlong(k);
#define DPP_RED(ctrl)                                                              \
    {                                                                              \
        unsigned int lo = (unsigned int)ku;                                        \
        unsigned int hi = (unsigned int)(ku >> 32);                                \
        unsigned int nlo =                                                         \
            (unsigned int)__builtin_amdgcn_update_dpp(0, (int)lo, ctrl, 0xf, 0xf, false); \
        unsigned int nhi =                                                         \
            (unsigned int)__builtin_amdgcn_update_dpp(0, (int)hi, ctrl, 0xf, 0xf, false); \
        double nk = __longlong_as_double(((unsigned long long)nhi << 32) | nlo);   \
        double cur = fmax(__longlong_as_double(ku), nk);                           \
        ku = __double_as_longlong(cur);                                            \
    }
    DPP_RED(0x111);  // row_shr:1
    DPP_RED(0x112);  // row_shr:2
    DPP_RED(0x114);  // row_shr:4
    DPP_RED(0x118);  // row_shr:8
    DPP_RED(0x142);  // row_bcast:15
    DPP_RED(0x143);  // row_bcast:31 -> lane 63 = all-64 max
#undef DPP_RED
    return __longlong_as_double(ku);
}

// ---------------------------------------------------------------------------
// Kernel 1: blocks 0..3 = FPS (one block per batch, 256 threads = 1 wave per
// SIMD); blocks 4.. pack (x, y, z, ||p||^2) of xyz_all into d_ws.
// 16 points/thread register-resident. Per iter: exact distance update
// ((dx*dx + dy*dy) + dz*dz, contraction off), f32 fminf running min,
// 16-key build + 15 v_max_f64 local tree, ONE DPP wave reduce per SIMD,
// 4-wave barrier, ds_read_b128 partials + 3 v_max_f64, broadcast sp read.
// [Known-good R4 structure: passed at 516.8 us fps / 584.9 us total.]
// ---------------------------------------------------------------------------
__global__ __launch_bounds__(FPS_T, 1) void fps_prep_kernel(
    const float* __restrict__ xyz_voxel,
    const float* __restrict__ normals_voxel,
    const float* __restrict__ xyz_all,
    float* __restrict__ out_xyz,      // (B, S, 3)
    float* __restrict__ out_normals,  // (B, S, 3)
    float4* __restrict__ ws_packed,   // (B, N_ALL) {x,y,z,pp}
    int do_prep)
{
#pragma clang fp contract(off)
    if (blockIdx.x >= B) {
        if (!do_prep) return;
        int pid = (blockIdx.x - B) * FPS_T + threadIdx.x;
        if (pid < B * N_ALL) {
            float x = xyz_all[pid * 3 + 0];
            float y = xyz_all[pid * 3 + 1];
            float z = xyz_all[pid * 3 + 2];
            float pp = __fadd_rn(__fadd_rn(__fmul_rn(x, x), __fmul_rn(y, y)),
                                 __fmul_rn(z, z));
            ws_packed[pid] = make_float4(x, y, z, pp);
        }
        return;
    }

    const int b = blockIdx.x;
    const int t = threadIdx.x;
    const int wid = t >> 6;    // 0..3
    const int lane = t & 63;

    __shared__ float4 sp[N_VOX];                       // 64 KB
    __shared__ int fps_idx_s[S_PTS];
    __shared__ alignas(16) unsigned long long s_part[2][FPS_T / 64];

    const float* xyz = xyz_voxel + (size_t)b * N_VOX * 3;
    for (int i = t; i < N_VOX; i += FPS_T) {
        float x = xyz[i * 3 + 0];
        float y = xyz[i * 3 + 1];
        float z = xyz[i * 3 + 2];
        sp[i] = make_float4(x, y, z, 0.0f);
    }
    __syncthreads();

    // Pair jp holds global points (2jp)*256 + t (lo) and (2jp+1)*256 + t (hi).
    vf2 px2[NPAIR], py2[NPAIR], pz2[NPAIR], dist2[NPAIR];
    unsigned int ilo[2 * NPAIR];
#pragma unroll
    for (int jp = 0; jp < NPAIR; jp++) {
        float4 a = sp[t + (2 * jp) * FPS_T];
        float4 c = sp[t + (2 * jp + 1) * FPS_T];
        px2[jp] = vf2{a.x, c.x};
        py2[jp] = vf2{a.y, c.y};
        pz2[jp] = vf2{a.z, c.z};
        dist2[jp] = vf2{1e10f, 1e10f};
        ilo[2 * jp]     = ~(unsigned int)((2 * jp) * FPS_T + t);
        ilo[2 * jp + 1] = ~(unsigned int)((2 * jp + 1) * FPS_T + t);
    }

    if (t == 0) fps_idx_s[0] = 0;
    float4 c0 = sp[0];
    float lx = c0.x, ly = c0.y, lz = c0.z;

    for (int step = 1; step < S_PTS; step++) {
        double kk[2 * NPAIR];
#pragma unroll
        for (int jp = 0; jp < NPAIR; jp++) {
            vf2 dx = px2[jp] - lx;
            vf2 dy = py2[jp] - ly;
            vf2 dz = pz2[jp] - lz;
            vf2 d = (dx * dx + dy * dy) + dz * dz;
            vf2 dm = dist2[jp];
            dm.x = fminf(dm.x, d.x);
            dm.y = fminf(dm.y, d.y);
            dist2[jp] = dm;
            kk[2 * jp]     = mk_key(dm.x, ilo[2 * jp]);
            kk[2 * jp + 1] = mk_key(dm.y, ilo[2 * jp + 1]);
        }
        // Local tree over 16 keys: 15 v_max_f64, depth 4.
        double m0 = fmax(fmax(kk[0], kk[1]),   fmax(kk[2], kk[3]));
        double m1 = fmax(fmax(kk[4], kk[5]),   fmax(kk[6], kk[7]));
        double m2 = fmax(fmax(kk[8], kk[9]),   fmax(kk[10], kk[11]));
        double m3 = fmax(fmax(kk[12], kk[13]), fmax(kk[14], kk[15]));
        double a0 = fmax(fmax(m0, m1), fmax(m2, m3));
        // One DPP wave reduce per SIMD (result in lane 63).
        a0 = wave_key_max_f64(a0);

        const int buf = step & 1;
        if (lane == 63)
            s_part[buf][wid] = (unsigned long long)__double_as_longlong(a0);
        __syncthreads();
        // 4 partials: one ds_read_b128 pair + 3 v_max_f64, all threads.
        double2 q0 = *((const double2*)&s_part[buf][0]);
        double2 q1 = *((const double2*)&s_part[buf][2]);
        double p0 = fmax(fmax(q0.x, q0.y), fmax(q1.x, q1.y));
        int besti = (int)(~(unsigned int)(unsigned long long)__double_as_longlong(p0))
                    & (N_VOX - 1);
        float4 cb = sp[besti];               // broadcast b128 read
        lx = cb.x; ly = cb.y; lz = cb.z;
        if (t == 0) fps_idx_s[step] = besti;
        // Double-buffered partials -> one barrier per iteration.
    }
    __syncthreads();

    for (int i = t; i < S_PTS; i += FPS_T) {
        int idx = fps_idx_s[i];
        int o = (b * S_PTS + i) * 3;
        float4 c = sp[idx];
        out_xyz[o + 0] = c.x;
        out_xyz[o + 1] = c.y;
        out_xyz[o + 2] = c.z;
        const float* nv = normals_voxel + ((size_t)b * N_VOX + idx) * 3;
        out_normals[o + 0] = nv[0];
        out_normals[o + 1] = nv[1];
        out_normals[o + 2] = nv[2];
    }
}

// ---------------------------------------------------------------------------
// Kernel 2: ball query + grouping. One wave per query. Groups of 4 chunks:
// 4 independent float4 loads up front, packed-fp32 d2, 4 in-order ballots.
// ---------------------------------------------------------------------------
template <bool PACKED>
__global__ __launch_bounds__(256) void ballquery_group_kernel(
    const float* __restrict__ xyz_all,   // (B, N_ALL, 3)
    const float* __restrict__ normals,   // (B, N_ALL, 3)
    const float* __restrict__ new_xyz,   // (B, S, 3)
    const float4* __restrict__ pw,       // (B, N_ALL) packed
    float* __restrict__ out_feat,        // (B, 3, S, K)
    float* __restrict__ out_featn)       // (B, 6, S, K)
{
#pragma clang fp contract(off)
    const int wid = threadIdx.x >> 6;
    const int lane = threadIdx.x & 63;
    const int q = blockIdx.x * 4 + wid;
    const int b = q >> 10;
    const int s = q & 1023;

    const float* xyz = xyz_all + (size_t)b * N_ALL * 3;
    const float* nrm = normals + (size_t)b * N_ALL * 3;
    const float4* pwb = PACKED ? (pw + (size_t)b * N_ALL) : nullptr;

    const float qx = new_xyz[q * 3 + 0];
    const float qy = new_xyz[q * 3 + 1];
    const float qz = new_xyz[q * 3 + 2];
    const float qq = __fadd_rn(__fadd_rn(__fmul_rn(qx, qx), __fmul_rn(qy, qy)),
                               __fmul_rn(qz, qz));

    __shared__ int sidx[4][K_SAMPLE];

    int cnt = 0;
    if (PACKED) {
        for (int g = 0; g < N_ALL / 256 && cnt < K_SAMPLE; g++) {
            int base = g * 256 + lane;
            float4 c0 = pwb[base];
            float4 c1 = pwb[base + 64];
            float4 c2 = pwb[base + 128];
            float4 c3 = pwb[base + 192];
            vf2 pxA = vf2{c0.x, c1.x}, pxB = vf2{c2.x, c3.x};
            vf2 pyA = vf2{c0.y, c1.y}, pyB = vf2{c2.y, c3.y};
            vf2 pzA = vf2{c0.z, c1.z}, pzB = vf2{c2.z, c3.z};
            vf2 ppA = vf2{c0.w, c1.w}, ppB = vf2{c2.w, c3.w};
            vf2 dtA = qx * pxA; dtA = dtA + qy * pyA; dtA = dtA + qz * pzA;
            vf2 dtB = qx * pxB; dtB = dtB + qy * pyB; dtB = dtB + qz * pzB;
            vf2 d2A = (qq + ppA) - 2.0f * dtA;
            vf2 d2B = (qq + ppB) - 2.0f * dtB;
            float d2s[4] = {d2A.x, d2A.y, d2B.x, d2B.y};
#pragma unroll
            for (int u = 0; u < 4; u++) {
                bool hit = d2s[u] < R2;
                unsigned long long mask = __ballot(hit);
                if (hit) {
                    int pos = cnt + __popcll(mask & ((1ull << lane) - 1ull));
                    if (pos < K_SAMPLE) sidx[wid][pos] = g * 256 + u * 64 + lane;
                }
                cnt += (int)__popcll(mask);
            }
        }
    } else {
        for (int c = 0; c < N_ALL / 64 && cnt < K_SAMPLE; c++) {
            int i = c * 64 + lane;
            float px = xyz[i * 3 + 0];
            float py = xyz[i * 3 + 1];
            float pz = xyz[i * 3 + 2];
            float pp = __fadd_rn(__fadd_rn(__fmul_rn(px, px), __fmul_rn(py, py)),
                                 __fmul_rn(pz, pz));
            float dt = __fadd_rn(__fadd_rn(__fmul_rn(qx, px), __fmul_rn(qy, py)),
                                 __fmul_rn(qz, pz));
            float d2 = __fsub_rn(__fadd_rn(qq, pp), __fmul_rn(2.0f, dt));
            bool hit = d2 < R2;
            unsigned long long mask = __ballot(hit);
            if (hit) {
                int pos = cnt + __popcll(mask & ((1ull << lane) - 1ull));
                if (pos < K_SAMPLE) sidx[wid][pos] = i;
            }
            cnt += (int)__popcll(mask);
        }
    }
    __syncthreads();

    if (lane < K_SAMPLE) {
        int idxj;
        if (cnt == 0)        idxj = 0;
        else if (lane < cnt) idxj = sidx[wid][lane];
        else                 idxj = sidx[wid][0];

        float px, py, pz;
        if (PACKED) {
            float4 cc = pwb[idxj];
            px = cc.x; py = cc.y; pz = cc.z;
        } else {
            px = xyz[idxj * 3 + 0];
            py = xyz[idxj * 3 + 1];
            pz = xyz[idxj * 3 + 2];
        }
        float rx = __fsub_rn(px, qx);
        float ry = __fsub_rn(py, qy);
        float rz = __fsub_rn(pz, qz);

        int o3 = ((b * 3) * S_PTS + s) * K_SAMPLE + lane;
        out_feat[o3 + 0 * 32768] = rx;
        out_feat[o3 + 1 * 32768] = ry;
        out_feat[o3 + 2 * 32768] = rz;

        float nx = nrm[idxj * 3 + 0];
        float ny = nrm[idxj * 3 + 1];
        float nz = nrm[idxj * 3 + 2];

        int o4 = ((b * 6) * S_PTS + s) * K_SAMPLE + lane;
        out_featn[o4 + 0 * 32768] = rx;
        out_featn[o4 + 1 * 32768] = ry;
        out_featn[o4 + 2 * 32768] = rz;
        out_featn[o4 + 3 * 32768] = nx;
        out_featn[o4 + 4 * 32768] = ny;
        out_featn[o4 + 5 * 32768] = nz;
    }
}

extern "C" void kernel_launch(void* const* d_in, const int* in_sizes, int n_in,
                              void* d_out, int out_size, void* d_ws, size_t ws_size,
                              hipStream_t stream) {
    const float* xyz_all       = (const float*)d_in[0];
    const float* normals       = (const float*)d_in[1];
    const float* xyz_voxel     = (const float*)d_in[2];
    const float* normals_voxel = (const float*)d_in[3];

    float* out = (float*)d_out;
    float* out_xyz     = out;           // (4, 1024, 3)     = 12288
    float* out_normals = out + 12288;   // (4, 1024, 3)     = 12288
    float* out_feat    = out + 24576;   // (4, 3, 1024, 32) = 393216
    float* out_featn   = out + 417792;  // (4, 6, 1024, 32) = 786432

    const size_t need = (size_t)B * N_ALL * sizeof(float4);   // 512 KB
    const bool use_ws = ws_size >= need;

    fps_prep_kernel<<<B + (use_ws ? PREP_BLOCKS : 0), FPS_T, 0, stream>>>(
        xyz_voxel, normals_voxel, xyz_all, out_xyz, out_normals,
        (float4*)d_ws, use_ws ? 1 : 0);

    if (use_ws) {
        ballquery_group_kernel<true><<<(B * S_PTS) / 4, 256, 0, stream>>>(
            xyz_all, normals, out_xyz, (const float4*)d_ws, out_feat, out_featn);
    } else {
        ballquery_group_kernel<false><<<(B * S_PTS) / 4, 256, 0, stream>>>(
            xyz_all, normals, out_xyz, nullptr, out_feat, out_featn);
    }
}